// Round 10
// baseline (430.577 us; speedup 1.0000x reference)
//
#include <hip/hip_runtime.h>
#include <stdint.h>

#define NH    16
#define HD    64
#define HDIM  1024
#define BATCH 4
#define SEQ   2048

typedef __attribute__((ext_vector_type(4))) float f32x4;
typedef __attribute__((ext_vector_type(8))) __bf16 bf16x8;
typedef __attribute__((ext_vector_type(8))) unsigned short u16x8;
typedef __attribute__((ext_vector_type(4))) unsigned short u16x4;

#define LOG2E 1.44269504088896340736f

__device__ __forceinline__ unsigned short f2bf(float f) {
  unsigned int u = __builtin_bit_cast(unsigned int, f);
  u += 0x7fffu + ((u >> 16) & 1u);   // RNE
  return (unsigned short)(u >> 16);
}

__device__ __forceinline__ f32x4 mfma16(u16x8 a, u16x8 b, f32x4 c) {
  return __builtin_amdgcn_mfma_f32_16x16x32_bf16(
      __builtin_bit_cast(bf16x8, a), __builtin_bit_cast(bf16x8, b), c, 0, 0, 0);
}

__device__ __forceinline__ f32x4 mfma16b(bf16x8 a, u16x8 b, f32x4 c) {
  return __builtin_amdgcn_mfma_f32_16x16x32_bf16(
      a, __builtin_bit_cast(bf16x8, b), c, 0, 0, 0);
}

__device__ __forceinline__ f32x4 mfma16bb(bf16x8 a, bf16x8 b, f32x4 c) {
  return __builtin_amdgcn_mfma_f32_16x16x32_bf16(a, b, c, 0, 0, 0);
}

#define GLOAD_LDS16(g, l)                                                      \
  __builtin_amdgcn_global_load_lds(                                            \
      (const __attribute__((address_space(1))) unsigned int*)(g),              \
      (__attribute__((address_space(3))) unsigned int*)(l), 16, 0, 0)

// ---------- fp32 -> bf16 bits, x8 vectorized ----------
__global__ __launch_bounds__(256) void cvt_x_kernel(
    const float* __restrict__ src, unsigned short* __restrict__ dst) {
  int i = (blockIdx.x * 256 + threadIdx.x) * 8;
  f32x4 a = *reinterpret_cast<const f32x4*>(src + i);
  f32x4 b = *reinterpret_cast<const f32x4*>(src + i + 4);
  u16x8 o;
  o[0] = f2bf(a[0]); o[1] = f2bf(a[1]); o[2] = f2bf(a[2]); o[3] = f2bf(a[3]);
  o[4] = f2bf(b[0]); o[5] = f2bf(b[1]); o[6] = f2bf(b[2]); o[7] = f2bf(b[3]);
  *reinterpret_cast<u16x8*>(dst + i) = o;
}

// ---------- W[k][n] fp32 -> Wcat[z][n][k] bf16, LDS-tiled transpose ----------
__global__ __launch_bounds__(256) void cvt_wt_kernel(
    const float* __restrict__ Wq, const float* __restrict__ Wk,
    const float* __restrict__ Wv, unsigned short* __restrict__ Wcat) {
  const float* __restrict__ src =
      (blockIdx.z == 0) ? Wq : (blockIdx.z == 1) ? Wk : Wv;
  unsigned short* __restrict__ dst = Wcat + (size_t)blockIdx.z * HDIM * HDIM;
  __shared__ float T[64][65];
  const int k0 = blockIdx.y * 64, n0 = blockIdx.x * 64;
  const int tid = threadIdx.x;
  const int lrow = tid >> 4, c4 = (tid & 15) * 4;
  for (int it = 0; it < 4; ++it) {
    f32x4 v = *reinterpret_cast<const f32x4*>(
        &src[(k0 + it * 16 + lrow) * HDIM + n0 + c4]);
    T[it * 16 + lrow][c4 + 0] = v[0];
    T[it * 16 + lrow][c4 + 1] = v[1];
    T[it * 16 + lrow][c4 + 2] = v[2];
    T[it * 16 + lrow][c4 + 3] = v[3];
  }
  __syncthreads();
  const int n = tid >> 2, kc = (tid & 3) * 16;
  u16x8 o0, o1;
  for (int j = 0; j < 8; ++j) o0[j] = f2bf(T[kc + j][n]);
  for (int j = 0; j < 8; ++j) o1[j] = f2bf(T[kc + 8 + j][n]);
  *reinterpret_cast<u16x8*>(&dst[(n0 + n) * HDIM + k0 + kc]) = o0;
  *reinterpret_cast<u16x8*>(&dst[(n0 + n) * HDIM + k0 + kc + 8]) = o1;
}

// ---------- fused QKV projection (unchanged from round 9) ----------
__global__ __launch_bounds__(256, 4) void proj_kernel(
    const unsigned short* __restrict__ Xb,
    const unsigned short* __restrict__ Wcat,
    const float* __restrict__ bq, const float* __restrict__ bk,
    const float* __restrict__ bv,
    unsigned short* __restrict__ Qs, unsigned short* __restrict__ Kb,
    unsigned short* __restrict__ Vt) {
  const int bid = blockIdx.x;
  const int xcd = bid & 7, i = bid >> 3;
  const int mi = xcd * 8 + (i & 7);
  const int ni = i >> 3;
  const int m0 = mi * 128;
  const int n0g = ni * 128;
  __shared__ unsigned short As[2][128 * 32];
  __shared__ unsigned short Bs[2][128 * 32];
  const int tid = threadIdx.x, lane = tid & 63, w = tid >> 6;
  const int wm = (w >> 1) * 64, wn = (w & 1) * 64;
  const int cl = lane & 15, rg = lane >> 4;
  f32x4 acc[4][4] = {};

#define PSTAGE(buf, k0)                                                        \
  do {                                                                         \
    for (int p = 0; p < 2; ++p) {                                              \
      int c = p * 256 + tid, row = c >> 2, ch = c & 3;                         \
      int sch = (ch ^ ((row >> 1) & 3)) * 8;                                   \
      GLOAD_LDS16(Xb + (m0 + row) * HDIM + (k0) + sch, &As[buf][c * 8]);       \
      GLOAD_LDS16(Wcat + (size_t)(n0g + row) * HDIM + (k0) + sch,              \
                  &Bs[buf][c * 8]);                                            \
    }                                                                          \
  } while (0)

  PSTAGE(0, 0);
  __syncthreads();
  for (int kt = 0; kt < HDIM / 32; ++kt) {
    const int cur = kt & 1;
    if (kt + 1 < HDIM / 32) PSTAGE(cur ^ 1, (kt + 1) * 32);
    u16x8 af[4], bfr[4];
    for (int m = 0; m < 4; ++m) {
      const int row = wm + m * 16 + cl;
      af[m] = *reinterpret_cast<const u16x8*>(
          &As[cur][row * 32 + ((rg ^ ((row >> 1) & 3)) * 8)]);
    }
    for (int n = 0; n < 4; ++n) {
      const int row = wn + n * 16 + cl;
      bfr[n] = *reinterpret_cast<const u16x8*>(
          &Bs[cur][row * 32 + ((rg ^ ((row >> 1) & 3)) * 8)]);
    }
    for (int m = 0; m < 4; ++m)
      for (int n = 0; n < 4; ++n)
        acc[m][n] = mfma16(af[m], bfr[n], acc[m][n]);
    __syncthreads();
  }
#undef PSTAGE

  const int z = n0g >> 10;
  const float* __restrict__ bias = (z == 0) ? bq : (z == 1) ? bk : bv;
  const int nbase = n0g & 1023;
  int hh[4], dd[4];
  float bvals[4];
  for (int n = 0; n < 4; ++n) {
    const int col = nbase + wn + n * 16 + cl;
    bvals[n] = bias[col];
    hh[n] = col >> 6;
    dd[n] = col & 63;
  }
  if (z == 2) {
    for (int n = 0; n < 4; ++n) {
      for (int m = 0; m < 4; ++m) {
        const int rbase = m0 + wm + m * 16 + rg * 4;
        const int b = rbase >> 11, s = rbase & 2047;
        u16x4 pk;
        for (int r = 0; r < 4; ++r) pk[r] = f2bf(acc[m][n][r] + bvals[n]);
        *reinterpret_cast<u16x4*>(
            &Vt[(((size_t)b * NH + hh[n]) * HD + dd[n]) * SEQ + s]) = pk;
      }
    }
  } else {
    unsigned short* __restrict__ dst = (z == 0) ? Qs : Kb;
    const float sc = (z == 0) ? (0.125f * LOG2E) : 1.0f;
    for (int m = 0; m < 4; ++m) {
      const int rbase = m0 + wm + m * 16 + rg * 4;
      const int b = rbase >> 11, s0 = rbase & 2047;
      for (int r = 0; r < 4; ++r) {
        const int srow = s0 + r;
        for (int n = 0; n < 4; ++n) {
          const float v = (acc[m][n][r] + bvals[n]) * sc;
          dst[(((size_t)b * NH + hh[n]) * SEQ + srow) * HD + dd[n]] = f2bf(v);
        }
      }
    }
  }
}

// ---------- flash attention v5: K LDS-staged, V direct-from-L2, ----------
// ---------- row-sum via ones-column MFMA (epilogue shuffles gone) ----------
// vs v4: (1) V is NOT staged -- each XCD's 8-head K/V set (4MB) is
// L2-resident by the bid remap, so V reads hit L2 (~200cy, hidden under
// exp2/pack); halves gload_lds traffic, barrier drain, b128 conflicts, and
// LDS (40->24KB). (2) lsum[rf] = mfma(pa, ones, lsum): D[q][*] = row-sum of
// P, already in ctx row layout -> kills 32 adds/tile + all epilogue shfl.
// (3) launch_bounds(256,5): 5 blocks/CU (VGPR cap 102).
#define SWZ(row) ((((row) & 3) << 1) | (((row) >> 3) & 1))
__global__ __launch_bounds__(256, 5) void attn_kernel(
    const unsigned short* __restrict__ Qs, const unsigned short* __restrict__ Kb,
    const unsigned short* __restrict__ Vt, const float* __restrict__ mask,
    float* __restrict__ out) {
  const int bid = blockIdx.x;
  const int lbid = (bid & 7) * 128 + (bid >> 3);
  const int head = lbid >> 4;
  const int qchunk = lbid & 15;
  const int b = head >> 4, h = head & 15;
  const int tid = threadIdx.x, lane = tid & 63, w = tid >> 6;
  const int q0 = qchunk * 128 + w * 32;
  const int cl = lane & 15, rg = lane >> 4;

  __shared__ unsigned short Kbuf[2][64 * 64];  // 16 KB [key][d], SWZ chunks
  __shared__ float Mlds[SEQ];                  // 8 KB mask*LOG2E

  {
    const float* mrow = mask + b * SEQ;
    f32x4 m0 = *reinterpret_cast<const f32x4*>(mrow + tid * 8);
    f32x4 m1 = *reinterpret_cast<const f32x4*>(mrow + tid * 8 + 4);
    for (int j = 0; j < 4; ++j) {
      Mlds[tid * 8 + j] = m0[j] * LOG2E;
      Mlds[tid * 8 + 4 + j] = m1[j] * LOG2E;
    }
  }

  const int srow0 = tid >> 3, ch0 = tid & 7;
  const int srow1 = 32 + srow0;
  const unsigned short* kgA = Kb + (head * SEQ + srow0) * HD + ((ch0 ^ SWZ(srow0)) * 8);
  const unsigned short* kgB = Kb + (head * SEQ + srow1) * HD + ((ch0 ^ SWZ(srow1)) * 8);
  const unsigned short* vbase = Vt + (size_t)head * HD * SEQ;

#define STAGE(buf, kk)                                                         \
  do {                                                                         \
    GLOAD_LDS16(kgA + (size_t)(kk)*HD, &Kbuf[buf][tid * 8]);                   \
    GLOAD_LDS16(kgB + (size_t)(kk)*HD, &Kbuf[buf][(256 + tid) * 8]);           \
  } while (0)

  u16x8 qf[2][2];
  for (int rf = 0; rf < 2; ++rf)
    for (int dc = 0; dc < 2; ++dc)
      qf[rf][dc] = *reinterpret_cast<const u16x8*>(
          Qs + (head * SEQ + q0 + rf * 16 + cl) * HD + dc * 32 + rg * 8);

  bf16x8 ones;
  for (int j = 0; j < 8; ++j) ones[j] = (__bf16)1.0f;

  f32x4 ctx[2][4] = {};
  f32x4 lsum[2] = {};

  STAGE(0, 0);
  __syncthreads();

  for (int t = 0; t < SEQ / 64; ++t) {
    const int cur = t & 1;
    const int kk = t * 64;
    if (t + 1 < SEQ / 64) STAGE(cur ^ 1, kk + 64);

    for (int jj = 0; jj < 2; ++jj) {
      f32x4 mv0 = *reinterpret_cast<const f32x4*>(&Mlds[kk + jj * 32 + rg * 8]);
      f32x4 mv1 = *reinterpret_cast<const f32x4*>(&Mlds[kk + jj * 32 + rg * 8 + 4]);
      f32x4 sT[2][2];
      sT[0][0] = mv0; sT[0][1] = mv0;
      sT[1][0] = mv1; sT[1][1] = mv1;
      __builtin_amdgcn_s_setprio(1);
      for (int c = 0; c < 2; ++c) {
        const int krow = jj * 32 + ((cl >> 2) << 3) + (c << 2) + (cl & 3);
        u16x8 kf0 = *reinterpret_cast<const u16x8*>(
            &Kbuf[cur][krow * 64 + ((rg ^ SWZ(krow)) * 8)]);
        u16x8 kf1 = *reinterpret_cast<const u16x8*>(
            &Kbuf[cur][krow * 64 + (((4 | rg) ^ SWZ(krow)) * 8)]);
        for (int rf = 0; rf < 2; ++rf) {
          sT[c][rf] = mfma16(kf0, qf[rf][0], sT[c][rf]);
          sT[c][rf] = mfma16(kf1, qf[rf][1], sT[c][rf]);
        }
      }
      __builtin_amdgcn_s_setprio(0);
      // V fragments direct from global (L2-resident); latency hides under
      // the exp2/pack chain below
      u16x8 vf[4];
      for (int df = 0; df < 4; ++df)
        vf[df] = *reinterpret_cast<const u16x8*>(
            vbase + ((size_t)(df * 16 + cl)) * SEQ + kk + (jj * 4 + rg) * 8);
      bf16x8 pa[2];
      for (int rf = 0; rf < 2; ++rf)
        for (int c = 0; c < 2; ++c)
          for (int r = 0; r < 4; ++r) {
            float p = __builtin_amdgcn_exp2f(sT[c][rf][r]);
            pa[rf][c * 4 + r] = (__bf16)p;
          }
      __builtin_amdgcn_s_setprio(1);
      for (int rf = 0; rf < 2; ++rf)
        lsum[rf] = mfma16bb(pa[rf], ones, lsum[rf]);
      for (int df = 0; df < 4; ++df)
        for (int rf = 0; rf < 2; ++rf)
          ctx[rf][df] = mfma16b(pa[rf], vf[df], ctx[rf][df]);
      __builtin_amdgcn_s_setprio(0);
    }
    __syncthreads();
  }

  // lsum[rf][r] = full row-sum for q-row rg*4+r (+rf*16), replicated over cl
  for (int rf = 0; rf < 2; ++rf) {
    f32x4 inv;
    for (int r = 0; r < 4; ++r) inv[r] = 1.0f / lsum[rf][r];
    for (int df = 0; df < 4; ++df)
      for (int r = 0; r < 4; ++r)
        out[(b * SEQ + q0 + rf * 16 + rg * 4 + r) * HDIM + h * HD + df * 16 + cl] =
            ctx[rf][df][r] * inv[r];
  }
#undef STAGE
}

extern "C" void kernel_launch(void* const* d_in, const int* in_sizes, int n_in,
                              void* d_out, int out_size, void* d_ws, size_t ws_size,
                              hipStream_t stream) {
  const float* hs   = (const float*)d_in[0];
  const float* mask = (const float*)d_in[1];
  // d_in[2] intent_ids, d_in[9..11] intent path: unused (softmax shift-invariant)
  const float* Wq = (const float*)d_in[3];
  const float* bq = (const float*)d_in[4];
  const float* Wk = (const float*)d_in[5];
  const float* bk = (const float*)d_in[6];
  const float* Wv = (const float*)d_in[7];
  const float* bv = (const float*)d_in[8];
  float* out = (float*)d_out;

  uint8_t* ws = (uint8_t*)d_ws;
  const size_t MB = 1024 * 1024;
  unsigned short* Xb   = (unsigned short*)(ws);            // 16 MB
  unsigned short* Wcat = (unsigned short*)(ws + 16 * MB);  // 6 MB: [3][1024][1024]
  unsigned short* Qsp  = (unsigned short*)(ws + 22 * MB);  // 16 MB: [64][2048][64]
  unsigned short* Kbp  = (unsigned short*)(ws + 38 * MB);  // 16 MB
  unsigned short* Vtp  = (unsigned short*)(ws + 54 * MB);  // 16 MB: [64][64][2048]

  cvt_x_kernel<<<4096, 256, 0, stream>>>(hs, Xb);
  cvt_wt_kernel<<<dim3(16, 16, 3), 256, 0, stream>>>(Wq, Wk, Wv, Wcat);
  proj_kernel<<<1536, 256, 0, stream>>>(Xb, Wcat, bq, bk, bv, Qsp, Kbp, Vtp);
  attn_kernel<<<1024, 256, 0, stream>>>(Qsp, Kbp, Vtp, mask, out);
}

// Round 11
// 206.934 us; speedup vs baseline: 2.0807x; 2.0807x over previous
//
#include <hip/hip_runtime.h>
#include <stdint.h>

#define NH    16
#define HD    64
#define HDIM  1024
#define BATCH 4
#define SEQ   2048

typedef __attribute__((ext_vector_type(4))) float f32x4;
typedef __attribute__((ext_vector_type(8))) __bf16 bf16x8;
typedef __attribute__((ext_vector_type(8))) unsigned short u16x8;
typedef __attribute__((ext_vector_type(4))) unsigned short u16x4;

#define LOG2E 1.44269504088896340736f

__device__ __forceinline__ unsigned short f2bf(float f) {
  unsigned int u = __builtin_bit_cast(unsigned int, f);
  u += 0x7fffu + ((u >> 16) & 1u);   // RNE
  return (unsigned short)(u >> 16);
}

__device__ __forceinline__ f32x4 mfma16(u16x8 a, u16x8 b, f32x4 c) {
  return __builtin_amdgcn_mfma_f32_16x16x32_bf16(
      __builtin_bit_cast(bf16x8, a), __builtin_bit_cast(bf16x8, b), c, 0, 0, 0);
}

__device__ __forceinline__ f32x4 mfma16b(bf16x8 a, u16x8 b, f32x4 c) {
  return __builtin_amdgcn_mfma_f32_16x16x32_bf16(
      a, __builtin_bit_cast(bf16x8, b), c, 0, 0, 0);
}

__device__ __forceinline__ f32x4 mfma16bb(bf16x8 a, bf16x8 b, f32x4 c) {
  return __builtin_amdgcn_mfma_f32_16x16x32_bf16(a, b, c, 0, 0, 0);
}

#define GLOAD_LDS16(g, l)                                                      \
  __builtin_amdgcn_global_load_lds(                                            \
      (const __attribute__((address_space(1))) unsigned int*)(g),              \
      (__attribute__((address_space(3))) unsigned int*)(l), 16, 0, 0)

// ---------- fp32 -> bf16 bits, x8 vectorized ----------
__global__ __launch_bounds__(256) void cvt_x_kernel(
    const float* __restrict__ src, unsigned short* __restrict__ dst) {
  int i = (blockIdx.x * 256 + threadIdx.x) * 8;
  f32x4 a = *reinterpret_cast<const f32x4*>(src + i);
  f32x4 b = *reinterpret_cast<const f32x4*>(src + i + 4);
  u16x8 o;
  o[0] = f2bf(a[0]); o[1] = f2bf(a[1]); o[2] = f2bf(a[2]); o[3] = f2bf(a[3]);
  o[4] = f2bf(b[0]); o[5] = f2bf(b[1]); o[6] = f2bf(b[2]); o[7] = f2bf(b[3]);
  *reinterpret_cast<u16x8*>(dst + i) = o;
}

// ---------- W[k][n] fp32 -> Wcat[z][n][k] bf16, LDS-tiled transpose ----------
__global__ __launch_bounds__(256) void cvt_wt_kernel(
    const float* __restrict__ Wq, const float* __restrict__ Wk,
    const float* __restrict__ Wv, unsigned short* __restrict__ Wcat) {
  const float* __restrict__ src =
      (blockIdx.z == 0) ? Wq : (blockIdx.z == 1) ? Wk : Wv;
  unsigned short* __restrict__ dst = Wcat + (size_t)blockIdx.z * HDIM * HDIM;
  __shared__ float T[64][65];
  const int k0 = blockIdx.y * 64, n0 = blockIdx.x * 64;
  const int tid = threadIdx.x;
  const int lrow = tid >> 4, c4 = (tid & 15) * 4;
  for (int it = 0; it < 4; ++it) {
    f32x4 v = *reinterpret_cast<const f32x4*>(
        &src[(k0 + it * 16 + lrow) * HDIM + n0 + c4]);
    T[it * 16 + lrow][c4 + 0] = v[0];
    T[it * 16 + lrow][c4 + 1] = v[1];
    T[it * 16 + lrow][c4 + 2] = v[2];
    T[it * 16 + lrow][c4 + 3] = v[3];
  }
  __syncthreads();
  const int n = tid >> 2, kc = (tid & 3) * 16;
  u16x8 o0, o1;
  for (int j = 0; j < 8; ++j) o0[j] = f2bf(T[kc + j][n]);
  for (int j = 0; j < 8; ++j) o1[j] = f2bf(T[kc + 8 + j][n]);
  *reinterpret_cast<u16x8*>(&dst[(n0 + n) * HDIM + k0 + kc]) = o0;
  *reinterpret_cast<u16x8*>(&dst[(n0 + n) * HDIM + k0 + kc + 8]) = o1;
}

// ---------- fused QKV projection (unchanged from round 9) ----------
__global__ __launch_bounds__(256, 4) void proj_kernel(
    const unsigned short* __restrict__ Xb,
    const unsigned short* __restrict__ Wcat,
    const float* __restrict__ bq, const float* __restrict__ bk,
    const float* __restrict__ bv,
    unsigned short* __restrict__ Qs, unsigned short* __restrict__ Kb,
    unsigned short* __restrict__ Vt) {
  const int bid = blockIdx.x;
  const int xcd = bid & 7, i = bid >> 3;
  const int mi = xcd * 8 + (i & 7);
  const int ni = i >> 3;
  const int m0 = mi * 128;
  const int n0g = ni * 128;
  __shared__ unsigned short As[2][128 * 32];
  __shared__ unsigned short Bs[2][128 * 32];
  const int tid = threadIdx.x, lane = tid & 63, w = tid >> 6;
  const int wm = (w >> 1) * 64, wn = (w & 1) * 64;
  const int cl = lane & 15, rg = lane >> 4;
  f32x4 acc[4][4] = {};

#define PSTAGE(buf, k0)                                                        \
  do {                                                                         \
    for (int p = 0; p < 2; ++p) {                                              \
      int c = p * 256 + tid, row = c >> 2, ch = c & 3;                         \
      int sch = (ch ^ ((row >> 1) & 3)) * 8;                                   \
      GLOAD_LDS16(Xb + (m0 + row) * HDIM + (k0) + sch, &As[buf][c * 8]);       \
      GLOAD_LDS16(Wcat + (size_t)(n0g + row) * HDIM + (k0) + sch,              \
                  &Bs[buf][c * 8]);                                            \
    }                                                                          \
  } while (0)

  PSTAGE(0, 0);
  __syncthreads();
  for (int kt = 0; kt < HDIM / 32; ++kt) {
    const int cur = kt & 1;
    if (kt + 1 < HDIM / 32) PSTAGE(cur ^ 1, (kt + 1) * 32);
    u16x8 af[4], bfr[4];
    for (int m = 0; m < 4; ++m) {
      const int row = wm + m * 16 + cl;
      af[m] = *reinterpret_cast<const u16x8*>(
          &As[cur][row * 32 + ((rg ^ ((row >> 1) & 3)) * 8)]);
    }
    for (int n = 0; n < 4; ++n) {
      const int row = wn + n * 16 + cl;
      bfr[n] = *reinterpret_cast<const u16x8*>(
          &Bs[cur][row * 32 + ((rg ^ ((row >> 1) & 3)) * 8)]);
    }
    for (int m = 0; m < 4; ++m)
      for (int n = 0; n < 4; ++n)
        acc[m][n] = mfma16(af[m], bfr[n], acc[m][n]);
    __syncthreads();
  }
#undef PSTAGE

  const int z = n0g >> 10;
  const float* __restrict__ bias = (z == 0) ? bq : (z == 1) ? bk : bv;
  const int nbase = n0g & 1023;
  int hh[4], dd[4];
  float bvals[4];
  for (int n = 0; n < 4; ++n) {
    const int col = nbase + wn + n * 16 + cl;
    bvals[n] = bias[col];
    hh[n] = col >> 6;
    dd[n] = col & 63;
  }
  if (z == 2) {
    for (int n = 0; n < 4; ++n) {
      for (int m = 0; m < 4; ++m) {
        const int rbase = m0 + wm + m * 16 + rg * 4;
        const int b = rbase >> 11, s = rbase & 2047;
        u16x4 pk;
        for (int r = 0; r < 4; ++r) pk[r] = f2bf(acc[m][n][r] + bvals[n]);
        *reinterpret_cast<u16x4*>(
            &Vt[(((size_t)b * NH + hh[n]) * HD + dd[n]) * SEQ + s]) = pk;
      }
    }
  } else {
    unsigned short* __restrict__ dst = (z == 0) ? Qs : Kb;
    const float sc = (z == 0) ? (0.125f * LOG2E) : 1.0f;
    for (int m = 0; m < 4; ++m) {
      const int rbase = m0 + wm + m * 16 + rg * 4;
      const int b = rbase >> 11, s0 = rbase & 2047;
      for (int r = 0; r < 4; ++r) {
        const int srow = s0 + r;
        for (int n = 0; n < 4; ++n) {
          const float v = (acc[m][n][r] + bvals[n]) * sc;
          dst[(((size_t)b * NH + hh[n]) * SEQ + srow) * HD + dd[n]] = f2bf(v);
        }
      }
    }
  }
}

// ---------- flash attention v5b: identical to v5 except launch_bounds ----------
// Round-10 lesson: LB(256,5) capped VGPRs at 48 << need -> scratch spills ->
// 853MB HBM writes, 4.6x slowdown. LB(256,4) gives cap 128 >= ~90 live.
#define SWZ(row) ((((row) & 3) << 1) | (((row) >> 3) & 1))
__global__ __launch_bounds__(256, 4) void attn_kernel(
    const unsigned short* __restrict__ Qs, const unsigned short* __restrict__ Kb,
    const unsigned short* __restrict__ Vt, const float* __restrict__ mask,
    float* __restrict__ out) {
  const int bid = blockIdx.x;
  const int lbid = (bid & 7) * 128 + (bid >> 3);
  const int head = lbid >> 4;
  const int qchunk = lbid & 15;
  const int b = head >> 4, h = head & 15;
  const int tid = threadIdx.x, lane = tid & 63, w = tid >> 6;
  const int q0 = qchunk * 128 + w * 32;
  const int cl = lane & 15, rg = lane >> 4;

  __shared__ unsigned short Kbuf[2][64 * 64];  // 16 KB [key][d], SWZ chunks
  __shared__ float Mlds[SEQ];                  // 8 KB mask*LOG2E

  {
    const float* mrow = mask + b * SEQ;
    f32x4 m0 = *reinterpret_cast<const f32x4*>(mrow + tid * 8);
    f32x4 m1 = *reinterpret_cast<const f32x4*>(mrow + tid * 8 + 4);
    for (int j = 0; j < 4; ++j) {
      Mlds[tid * 8 + j] = m0[j] * LOG2E;
      Mlds[tid * 8 + 4 + j] = m1[j] * LOG2E;
    }
  }

  const int srow0 = tid >> 3, ch0 = tid & 7;
  const int srow1 = 32 + srow0;
  const unsigned short* kgA = Kb + (head * SEQ + srow0) * HD + ((ch0 ^ SWZ(srow0)) * 8);
  const unsigned short* kgB = Kb + (head * SEQ + srow1) * HD + ((ch0 ^ SWZ(srow1)) * 8);
  const unsigned short* vbase = Vt + (size_t)head * HD * SEQ;

#define STAGE(buf, kk)                                                         \
  do {                                                                         \
    GLOAD_LDS16(kgA + (size_t)(kk)*HD, &Kbuf[buf][tid * 8]);                   \
    GLOAD_LDS16(kgB + (size_t)(kk)*HD, &Kbuf[buf][(256 + tid) * 8]);           \
  } while (0)

  u16x8 qf[2][2];
  for (int rf = 0; rf < 2; ++rf)
    for (int dc = 0; dc < 2; ++dc)
      qf[rf][dc] = *reinterpret_cast<const u16x8*>(
          Qs + (head * SEQ + q0 + rf * 16 + cl) * HD + dc * 32 + rg * 8);

  bf16x8 ones;
  for (int j = 0; j < 8; ++j) ones[j] = (__bf16)1.0f;

  f32x4 ctx[2][4] = {};
  f32x4 lsum[2] = {};

  STAGE(0, 0);
  __syncthreads();

  for (int t = 0; t < SEQ / 64; ++t) {
    const int cur = t & 1;
    const int kk = t * 64;
    if (t + 1 < SEQ / 64) STAGE(cur ^ 1, kk + 64);

    for (int jj = 0; jj < 2; ++jj) {
      f32x4 mv0 = *reinterpret_cast<const f32x4*>(&Mlds[kk + jj * 32 + rg * 8]);
      f32x4 mv1 = *reinterpret_cast<const f32x4*>(&Mlds[kk + jj * 32 + rg * 8 + 4]);
      f32x4 sT[2][2];
      sT[0][0] = mv0; sT[0][1] = mv0;
      sT[1][0] = mv1; sT[1][1] = mv1;
      __builtin_amdgcn_s_setprio(1);
      for (int c = 0; c < 2; ++c) {
        const int krow = jj * 32 + ((cl >> 2) << 3) + (c << 2) + (cl & 3);
        u16x8 kf0 = *reinterpret_cast<const u16x8*>(
            &Kbuf[cur][krow * 64 + ((rg ^ SWZ(krow)) * 8)]);
        u16x8 kf1 = *reinterpret_cast<const u16x8*>(
            &Kbuf[cur][krow * 64 + (((4 | rg) ^ SWZ(krow)) * 8)]);
        for (int rf = 0; rf < 2; ++rf) {
          sT[c][rf] = mfma16(kf0, qf[rf][0], sT[c][rf]);
          sT[c][rf] = mfma16(kf1, qf[rf][1], sT[c][rf]);
        }
      }
      __builtin_amdgcn_s_setprio(0);
      // V fragments direct from global (L2-resident); latency hides under
      // the exp2/pack chain below
      u16x8 vf[4];
      for (int df = 0; df < 4; ++df)
        vf[df] = *reinterpret_cast<const u16x8*>(
            vbase + ((size_t)(df * 16 + cl)) * SEQ + kk + (jj * 4 + rg) * 8);
      bf16x8 pa[2];
      for (int rf = 0; rf < 2; ++rf)
        for (int c = 0; c < 2; ++c)
          for (int r = 0; r < 4; ++r) {
            float p = __builtin_amdgcn_exp2f(sT[c][rf][r]);
            pa[rf][c * 4 + r] = (__bf16)p;
          }
      __builtin_amdgcn_s_setprio(1);
      for (int rf = 0; rf < 2; ++rf)
        lsum[rf] = mfma16bb(pa[rf], ones, lsum[rf]);
      for (int df = 0; df < 4; ++df)
        for (int rf = 0; rf < 2; ++rf)
          ctx[rf][df] = mfma16b(pa[rf], vf[df], ctx[rf][df]);
      __builtin_amdgcn_s_setprio(0);
    }
    __syncthreads();
  }

  // lsum[rf][r] = full row-sum for q-row rg*4+r (+rf*16), replicated over cl
  for (int rf = 0; rf < 2; ++rf) {
    f32x4 inv;
    for (int r = 0; r < 4; ++r) inv[r] = 1.0f / lsum[rf][r];
    for (int df = 0; df < 4; ++df)
      for (int r = 0; r < 4; ++r)
        out[(b * SEQ + q0 + rf * 16 + rg * 4 + r) * HDIM + h * HD + df * 16 + cl] =
            ctx[rf][df][r] * inv[r];
  }
#undef STAGE
}

extern "C" void kernel_launch(void* const* d_in, const int* in_sizes, int n_in,
                              void* d_out, int out_size, void* d_ws, size_t ws_size,
                              hipStream_t stream) {
  const float* hs   = (const float*)d_in[0];
  const float* mask = (const float*)d_in[1];
  // d_in[2] intent_ids, d_in[9..11] intent path: unused (softmax shift-invariant)
  const float* Wq = (const float*)d_in[3];
  const float* bq = (const float*)d_in[4];
  const float* Wk = (const float*)d_in[5];
  const float* bk = (const float*)d_in[6];
  const float* Wv = (const float*)d_in[7];
  const float* bv = (const float*)d_in[8];
  float* out = (float*)d_out;

  uint8_t* ws = (uint8_t*)d_ws;
  const size_t MB = 1024 * 1024;
  unsigned short* Xb   = (unsigned short*)(ws);            // 16 MB
  unsigned short* Wcat = (unsigned short*)(ws + 16 * MB);  // 6 MB: [3][1024][1024]
  unsigned short* Qsp  = (unsigned short*)(ws + 22 * MB);  // 16 MB: [64][2048][64]
  unsigned short* Kbp  = (unsigned short*)(ws + 38 * MB);  // 16 MB
  unsigned short* Vtp  = (unsigned short*)(ws + 54 * MB);  // 16 MB: [64][64][2048]

  cvt_x_kernel<<<4096, 256, 0, stream>>>(hs, Xb);
  cvt_wt_kernel<<<dim3(16, 16, 3), 256, 0, stream>>>(Wq, Wk, Wv, Wcat);
  proj_kernel<<<1536, 256, 0, stream>>>(Xb, Wcat, bq, bk, bv, Qsp, Kbp, Vtp);
  attn_kernel<<<1024, 256, 0, stream>>>(Qsp, Kbp, Vtp, mask, out);
}

// Round 12
// 152.311 us; speedup vs baseline: 2.8270x; 1.3586x over previous
//
#include <hip/hip_runtime.h>
#include <stdint.h>

#define NH    16
#define HD    64
#define HDIM  1024
#define BATCH 4
#define SEQ   2048

typedef __attribute__((ext_vector_type(4))) float f32x4;
typedef __attribute__((ext_vector_type(8))) __bf16 bf16x8;
typedef __attribute__((ext_vector_type(8))) unsigned short u16x8;
typedef __attribute__((ext_vector_type(4))) unsigned short u16x4;

#define LOG2E 1.44269504088896340736f

__device__ __forceinline__ unsigned short f2bf(float f) {
  unsigned int u = __builtin_bit_cast(unsigned int, f);
  u += 0x7fffu + ((u >> 16) & 1u);   // RNE
  return (unsigned short)(u >> 16);
}

__device__ __forceinline__ f32x4 mfma16(u16x8 a, u16x8 b, f32x4 c) {
  return __builtin_amdgcn_mfma_f32_16x16x32_bf16(
      __builtin_bit_cast(bf16x8, a), __builtin_bit_cast(bf16x8, b), c, 0, 0, 0);
}

__device__ __forceinline__ f32x4 mfma16b(bf16x8 a, u16x8 b, f32x4 c) {
  return __builtin_amdgcn_mfma_f32_16x16x32_bf16(
      a, __builtin_bit_cast(bf16x8, b), c, 0, 0, 0);
}

__device__ __forceinline__ f32x4 mfma16bb(bf16x8 a, bf16x8 b, f32x4 c) {
  return __builtin_amdgcn_mfma_f32_16x16x32_bf16(a, b, c, 0, 0, 0);
}

#define GLOAD_LDS16(g, l)                                                      \
  __builtin_amdgcn_global_load_lds(                                            \
      (const __attribute__((address_space(1))) unsigned int*)(g),              \
      (__attribute__((address_space(3))) unsigned int*)(l), 16, 0, 0)

// ---------- fp32 -> bf16 bits, x8 vectorized ----------
__global__ __launch_bounds__(256) void cvt_x_kernel(
    const float* __restrict__ src, unsigned short* __restrict__ dst) {
  int i = (blockIdx.x * 256 + threadIdx.x) * 8;
  f32x4 a = *reinterpret_cast<const f32x4*>(src + i);
  f32x4 b = *reinterpret_cast<const f32x4*>(src + i + 4);
  u16x8 o;
  o[0] = f2bf(a[0]); o[1] = f2bf(a[1]); o[2] = f2bf(a[2]); o[3] = f2bf(a[3]);
  o[4] = f2bf(b[0]); o[5] = f2bf(b[1]); o[6] = f2bf(b[2]); o[7] = f2bf(b[3]);
  *reinterpret_cast<u16x8*>(dst + i) = o;
}

// ---------- W[k][n] fp32 -> Wcat[z][n][k] bf16, LDS-tiled transpose ----------
__global__ __launch_bounds__(256) void cvt_wt_kernel(
    const float* __restrict__ Wq, const float* __restrict__ Wk,
    const float* __restrict__ Wv, unsigned short* __restrict__ Wcat) {
  const float* __restrict__ src =
      (blockIdx.z == 0) ? Wq : (blockIdx.z == 1) ? Wk : Wv;
  unsigned short* __restrict__ dst = Wcat + (size_t)blockIdx.z * HDIM * HDIM;
  __shared__ float T[64][65];
  const int k0 = blockIdx.y * 64, n0 = blockIdx.x * 64;
  const int tid = threadIdx.x;
  const int lrow = tid >> 4, c4 = (tid & 15) * 4;
  for (int it = 0; it < 4; ++it) {
    f32x4 v = *reinterpret_cast<const f32x4*>(
        &src[(k0 + it * 16 + lrow) * HDIM + n0 + c4]);
    T[it * 16 + lrow][c4 + 0] = v[0];
    T[it * 16 + lrow][c4 + 1] = v[1];
    T[it * 16 + lrow][c4 + 2] = v[2];
    T[it * 16 + lrow][c4 + 3] = v[3];
  }
  __syncthreads();
  const int n = tid >> 2, kc = (tid & 3) * 16;
  u16x8 o0, o1;
  for (int j = 0; j < 8; ++j) o0[j] = f2bf(T[kc + j][n]);
  for (int j = 0; j < 8; ++j) o1[j] = f2bf(T[kc + 8 + j][n]);
  *reinterpret_cast<u16x8*>(&dst[(n0 + n) * HDIM + k0 + kc]) = o0;
  *reinterpret_cast<u16x8*>(&dst[(n0 + n) * HDIM + k0 + kc + 8]) = o1;
}

// ---------- fused QKV projection (unchanged from round 9) ----------
__global__ __launch_bounds__(256, 4) void proj_kernel(
    const unsigned short* __restrict__ Xb,
    const unsigned short* __restrict__ Wcat,
    const float* __restrict__ bq, const float* __restrict__ bk,
    const float* __restrict__ bv,
    unsigned short* __restrict__ Qs, unsigned short* __restrict__ Kb,
    unsigned short* __restrict__ Vt) {
  const int bid = blockIdx.x;
  const int xcd = bid & 7, i = bid >> 3;
  const int mi = xcd * 8 + (i & 7);
  const int ni = i >> 3;
  const int m0 = mi * 128;
  const int n0g = ni * 128;
  __shared__ unsigned short As[2][128 * 32];
  __shared__ unsigned short Bs[2][128 * 32];
  const int tid = threadIdx.x, lane = tid & 63, w = tid >> 6;
  const int wm = (w >> 1) * 64, wn = (w & 1) * 64;
  const int cl = lane & 15, rg = lane >> 4;
  f32x4 acc[4][4] = {};

#define PSTAGE(buf, k0)                                                        \
  do {                                                                         \
    for (int p = 0; p < 2; ++p) {                                              \
      int c = p * 256 + tid, row = c >> 2, ch = c & 3;                         \
      int sch = (ch ^ ((row >> 1) & 3)) * 8;                                   \
      GLOAD_LDS16(Xb + (m0 + row) * HDIM + (k0) + sch, &As[buf][c * 8]);       \
      GLOAD_LDS16(Wcat + (size_t)(n0g + row) * HDIM + (k0) + sch,              \
                  &Bs[buf][c * 8]);                                            \
    }                                                                          \
  } while (0)

  PSTAGE(0, 0);
  __syncthreads();
  for (int kt = 0; kt < HDIM / 32; ++kt) {
    const int cur = kt & 1;
    if (kt + 1 < HDIM / 32) PSTAGE(cur ^ 1, (kt + 1) * 32);
    u16x8 af[4], bfr[4];
    for (int m = 0; m < 4; ++m) {
      const int row = wm + m * 16 + cl;
      af[m] = *reinterpret_cast<const u16x8*>(
          &As[cur][row * 32 + ((rg ^ ((row >> 1) & 3)) * 8)]);
    }
    for (int n = 0; n < 4; ++n) {
      const int row = wn + n * 16 + cl;
      bfr[n] = *reinterpret_cast<const u16x8*>(
          &Bs[cur][row * 32 + ((rg ^ ((row >> 1) & 3)) * 8)]);
    }
    for (int m = 0; m < 4; ++m)
      for (int n = 0; n < 4; ++n)
        acc[m][n] = mfma16(af[m], bfr[n], acc[m][n]);
    __syncthreads();
  }
#undef PSTAGE

  const int z = n0g >> 10;
  const float* __restrict__ bias = (z == 0) ? bq : (z == 1) ? bk : bv;
  const int nbase = n0g & 1023;
  int hh[4], dd[4];
  float bvals[4];
  for (int n = 0; n < 4; ++n) {
    const int col = nbase + wn + n * 16 + cl;
    bvals[n] = bias[col];
    hh[n] = col >> 6;
    dd[n] = col & 63;
  }
  if (z == 2) {
    for (int n = 0; n < 4; ++n) {
      for (int m = 0; m < 4; ++m) {
        const int rbase = m0 + wm + m * 16 + rg * 4;
        const int b = rbase >> 11, s = rbase & 2047;
        u16x4 pk;
        for (int r = 0; r < 4; ++r) pk[r] = f2bf(acc[m][n][r] + bvals[n]);
        *reinterpret_cast<u16x4*>(
            &Vt[(((size_t)b * NH + hh[n]) * HD + dd[n]) * SEQ + s]) = pk;
      }
    }
  } else {
    unsigned short* __restrict__ dst = (z == 0) ? Qs : Kb;
    const float sc = (z == 0) ? (0.125f * LOG2E) : 1.0f;
    for (int m = 0; m < 4; ++m) {
      const int rbase = m0 + wm + m * 16 + rg * 4;
      const int b = rbase >> 11, s0 = rbase & 2047;
      for (int r = 0; r < 4; ++r) {
        const int srow = s0 + r;
        for (int n = 0; n < 4; ++n) {
          const float v = (acc[m][n][r] + bvals[n]) * sc;
          dst[(((size_t)b * NH + hh[n]) * SEQ + srow) * HD + dd[n]] = f2bf(v);
        }
      }
    }
  }
}

// ---------- flash attention v6: round-9 v4 staging + lsum-MFMA ----------
// Staging/structure byte-identical to the proven 82.4us v4 (K AND V both
// LDS-staged via gload_lds, 40KB, LB(256,4), mask as MFMA C-init, native
// bf16 pack, setprio). Round-11 lesson applied: V-direct-from-L2 is a loss
// (uncoalesced 4KB-stride reads on the critical path). Only retained v5
// idea: lsum[rf] = mfma(pa, ones) row-sum (correctness proven rounds 10-11)
// -- replaces 32 v_add/tile + 12-shuffle epilogue with 4 MFMA/tile on the
// less-loaded matrix pipe (round-9 was at the 78% VALU+MFMA co-issue
// ceiling; this shifts work off the VALU side).
#define SWZ(row) ((((row) & 3) << 1) | (((row) >> 3) & 1))
__global__ __launch_bounds__(256, 4) void attn_kernel(
    const unsigned short* __restrict__ Qs, const unsigned short* __restrict__ Kb,
    const unsigned short* __restrict__ Vt, const float* __restrict__ mask,
    float* __restrict__ out) {
  const int bid = blockIdx.x;
  const int lbid = (bid & 7) * 128 + (bid >> 3);
  const int head = lbid >> 4;
  const int qchunk = lbid & 15;
  const int b = head >> 4, h = head & 15;
  const int tid = threadIdx.x, lane = tid & 63, w = tid >> 6;
  const int q0 = qchunk * 128 + w * 32;
  const int cl = lane & 15, rg = lane >> 4;

  __shared__ unsigned short Kbuf[2][64 * 64];  // 16 KB [key][d], SWZ chunks
  __shared__ unsigned short Vbuf[2][64 * 64];  // 16 KB [d][key], SWZ chunks
  __shared__ float Mlds[SEQ];                  // 8 KB mask*LOG2E

  {
    const float* mrow = mask + b * SEQ;
    f32x4 m0 = *reinterpret_cast<const f32x4*>(mrow + tid * 8);
    f32x4 m1 = *reinterpret_cast<const f32x4*>(mrow + tid * 8 + 4);
    for (int j = 0; j < 4; ++j) {
      Mlds[tid * 8 + j] = m0[j] * LOG2E;
      Mlds[tid * 8 + 4 + j] = m1[j] * LOG2E;
    }
  }

  const int srow0 = tid >> 3, ch0 = tid & 7;
  const int srow1 = 32 + srow0;
  const unsigned short* kgA = Kb + (head * SEQ + srow0) * HD + ((ch0 ^ SWZ(srow0)) * 8);
  const unsigned short* kgB = Kb + (head * SEQ + srow1) * HD + ((ch0 ^ SWZ(srow1)) * 8);
  const unsigned short* vgA = Vt + (head * HD + srow0) * SEQ + ((ch0 ^ SWZ(srow0)) * 8);
  const unsigned short* vgB = Vt + (head * HD + srow1) * SEQ + ((ch0 ^ SWZ(srow1)) * 8);

#define STAGE(buf, kk)                                                         \
  do {                                                                         \
    GLOAD_LDS16(kgA + (size_t)(kk)*HD, &Kbuf[buf][tid * 8]);                   \
    GLOAD_LDS16(kgB + (size_t)(kk)*HD, &Kbuf[buf][(256 + tid) * 8]);           \
    GLOAD_LDS16(vgA + (kk), &Vbuf[buf][tid * 8]);                              \
    GLOAD_LDS16(vgB + (kk), &Vbuf[buf][(256 + tid) * 8]);                      \
  } while (0)

  u16x8 qf[2][2];
  for (int rf = 0; rf < 2; ++rf)
    for (int dc = 0; dc < 2; ++dc)
      qf[rf][dc] = *reinterpret_cast<const u16x8*>(
          Qs + (head * SEQ + q0 + rf * 16 + cl) * HD + dc * 32 + rg * 8);

  bf16x8 ones;
  for (int j = 0; j < 8; ++j) ones[j] = (__bf16)1.0f;

  f32x4 ctx[2][4] = {};
  f32x4 lsum[2] = {};

  STAGE(0, 0);
  __syncthreads();

  for (int t = 0; t < SEQ / 64; ++t) {
    const int cur = t & 1;
    const int kk = t * 64;
    if (t + 1 < SEQ / 64) STAGE(cur ^ 1, kk + 64);

    for (int jj = 0; jj < 2; ++jj) {
      f32x4 mv0 = *reinterpret_cast<const f32x4*>(&Mlds[kk + jj * 32 + rg * 8]);
      f32x4 mv1 = *reinterpret_cast<const f32x4*>(&Mlds[kk + jj * 32 + rg * 8 + 4]);
      f32x4 sT[2][2];
      sT[0][0] = mv0; sT[0][1] = mv0;
      sT[1][0] = mv1; sT[1][1] = mv1;
      __builtin_amdgcn_s_setprio(1);
      for (int c = 0; c < 2; ++c) {
        const int krow = jj * 32 + ((cl >> 2) << 3) + (c << 2) + (cl & 3);
        u16x8 kf0 = *reinterpret_cast<const u16x8*>(
            &Kbuf[cur][krow * 64 + ((rg ^ SWZ(krow)) * 8)]);
        u16x8 kf1 = *reinterpret_cast<const u16x8*>(
            &Kbuf[cur][krow * 64 + (((4 | rg) ^ SWZ(krow)) * 8)]);
        for (int rf = 0; rf < 2; ++rf) {
          sT[c][rf] = mfma16(kf0, qf[rf][0], sT[c][rf]);
          sT[c][rf] = mfma16(kf1, qf[rf][1], sT[c][rf]);
        }
      }
      __builtin_amdgcn_s_setprio(0);
      bf16x8 pa[2];
      for (int rf = 0; rf < 2; ++rf)
        for (int c = 0; c < 2; ++c)
          for (int r = 0; r < 4; ++r) {
            float p = __builtin_amdgcn_exp2f(sT[c][rf][r]);
            pa[rf][c * 4 + r] = (__bf16)p;
          }
      __builtin_amdgcn_s_setprio(1);
      for (int rf = 0; rf < 2; ++rf)
        lsum[rf] = mfma16bb(pa[rf], ones, lsum[rf]);
      for (int df = 0; df < 4; ++df) {
        const int vrow = df * 16 + cl;
        u16x8 vf = *reinterpret_cast<const u16x8*>(
            &Vbuf[cur][vrow * 64 + (((jj * 4 + rg) ^ SWZ(vrow)) * 8)]);
        for (int rf = 0; rf < 2; ++rf)
          ctx[rf][df] = mfma16b(pa[rf], vf, ctx[rf][df]);
      }
      __builtin_amdgcn_s_setprio(0);
    }
    __syncthreads();
  }

  // lsum[rf][r] = full row-sum for q-row rg*4+r (+rf*16), replicated over cl
  for (int rf = 0; rf < 2; ++rf) {
    f32x4 inv;
    for (int r = 0; r < 4; ++r) inv[r] = 1.0f / lsum[rf][r];
    for (int df = 0; df < 4; ++df)
      for (int r = 0; r < 4; ++r)
        out[(b * SEQ + q0 + rf * 16 + rg * 4 + r) * HDIM + h * HD + df * 16 + cl] =
            ctx[rf][df][r] * inv[r];
  }
#undef STAGE
}

extern "C" void kernel_launch(void* const* d_in, const int* in_sizes, int n_in,
                              void* d_out, int out_size, void* d_ws, size_t ws_size,
                              hipStream_t stream) {
  const float* hs   = (const float*)d_in[0];
  const float* mask = (const float*)d_in[1];
  // d_in[2] intent_ids, d_in[9..11] intent path: unused (softmax shift-invariant)
  const float* Wq = (const float*)d_in[3];
  const float* bq = (const float*)d_in[4];
  const float* Wk = (const float*)d_in[5];
  const float* bk = (const float*)d_in[6];
  const float* Wv = (const float*)d_in[7];
  const float* bv = (const float*)d_in[8];
  float* out = (float*)d_out;

  uint8_t* ws = (uint8_t*)d_ws;
  const size_t MB = 1024 * 1024;
  unsigned short* Xb   = (unsigned short*)(ws);            // 16 MB
  unsigned short* Wcat = (unsigned short*)(ws + 16 * MB);  // 6 MB: [3][1024][1024]
  unsigned short* Qsp  = (unsigned short*)(ws + 22 * MB);  // 16 MB: [64][2048][64]
  unsigned short* Kbp  = (unsigned short*)(ws + 38 * MB);  // 16 MB
  unsigned short* Vtp  = (unsigned short*)(ws + 54 * MB);  // 16 MB: [64][64][2048]

  cvt_x_kernel<<<4096, 256, 0, stream>>>(hs, Xb);
  cvt_wt_kernel<<<dim3(16, 16, 3), 256, 0, stream>>>(Wq, Wk, Wv, Wcat);
  proj_kernel<<<1536, 256, 0, stream>>>(Xb, Wcat, bq, bk, bv, Qsp, Kbp, Vtp);
  attn_kernel<<<1024, 256, 0, stream>>>(Qsp, Kbp, Vtp, mask, out);
}